// Round 5
// baseline (329.051 us; speedup 1.0000x reference)
//
#include <hip/hip_runtime.h>
#include <stdint.h>

#define BATCH 8
#define SEQ 2048
#define DIM 1024
#define MTOT (BATCH * SEQ)   // 16384
#define SC_CH 64             // scan chunks per batch
#define SC_T 32              // timesteps per chunk

typedef __attribute__((ext_vector_type(8))) short short8;
typedef __attribute__((ext_vector_type(8))) unsigned short ushort8;
typedef __attribute__((ext_vector_type(4))) float floatx4;

// ---------- helpers ----------

__device__ __forceinline__ unsigned short f2bf(float f) {
  union { float f; unsigned u; } c; c.f = f;
  unsigned u = c.u;
  return (unsigned short)((u + 0x7FFFu + ((u >> 16) & 1u)) >> 16);
}
__device__ __forceinline__ float bf2f(unsigned short h) {
  union { unsigned u; float f; } c; c.u = ((unsigned)h) << 16;
  return c.f;
}

__device__ __forceinline__ void gll16(const void* g, void* l) {
  __builtin_amdgcn_global_load_lds(
      (__attribute__((address_space(1))) void*)(uintptr_t)g,
      (__attribute__((address_space(3))) void*)(uintptr_t)l,
      16, 0, 0);
}

// ---------- fused cast fp32->bf16 for x, B, W + zero flags/ticket ----------

#define XN8 (MTOT * DIM / 8)   // 2097152
#define MN8 (DIM * DIM / 8)    // 131072

__global__ __launch_bounds__(256) void cast3_kernel(
    const float* __restrict__ x, const float* __restrict__ B,
    const float* __restrict__ W, unsigned short* __restrict__ xb,
    unsigned short* __restrict__ Bb, unsigned short* __restrict__ Wb,
    unsigned* __restrict__ flags /* 512 flags + ticket */) {
  int i = blockIdx.x * 256 + threadIdx.x;
  if (blockIdx.x == 0) {
    for (int w = threadIdx.x; w < 544; w += 256) flags[w] = 0u;
  }
  const float* src;
  unsigned short* dst;
  int li;
  if (i < XN8) {
    src = x; dst = xb; li = i;
  } else if (i < XN8 + MN8) {
    src = B; dst = Bb; li = i - XN8;
  } else {
    src = W; dst = Wb; li = i - XN8 - MN8;
  }
  const float4* s4 = (const float4*)src;
  float4 a = s4[2 * li], b = s4[2 * li + 1];
  uint4 o;
  o.x = (unsigned)f2bf(a.x) | ((unsigned)f2bf(a.y) << 16);
  o.y = (unsigned)f2bf(a.z) | ((unsigned)f2bf(a.w) << 16);
  o.z = (unsigned)f2bf(b.x) | ((unsigned)f2bf(b.y) << 16);
  o.w = (unsigned)f2bf(b.z) | ((unsigned)f2bf(b.w) << 16);
  ((uint4*)dst)[li] = o;
}

// ---------- NT GEMM (round-2 verbatim: measured FETCH=ideal, 0 conflicts) ----

template <bool OUT_BF16>
__global__ __launch_bounds__(256) void gemm_nt(
    const unsigned short* __restrict__ A,  // [M x K] bf16
    const unsigned short* __restrict__ B,  // [N x K] bf16
    void* __restrict__ Cp,                 // bf16 [MxN] or fp32 [MxN]
    const float* __restrict__ bias,        // used when !OUT_BF16
    int K, int N) {
  __shared__ unsigned short smem[16384];  // sA(8K shorts)|sB(8K shorts), reused sC
  unsigned short* sA = smem;
  unsigned short* sB = smem + 8192;

  const int tid = threadIdx.x;
  const int wave = tid >> 6, lane = tid & 63;

  // XCD-aware tile remap: XCD = id&7 owns a 16-m-tile band x all 8 n-tiles.
  const int id = blockIdx.x;
  const int xcd = id & 7, j = id >> 3;
  const int mt = xcd * 16 + (j >> 3);
  const int nt = j & 7;
  const size_t m0 = (size_t)mt * 128;
  const int n0 = nt * 128;

  floatx4 acc[4][4] = {};

  const int srow = wave * 8 + (lane >> 3);
  const int scol = (((lane & 7) ^ ((lane >> 3) & 7)) * 8);  // XOR swizzle
  const unsigned short* gA = A + (m0 + srow) * (size_t)K + scol;
  const unsigned short* gB = B + ((size_t)n0 + srow) * (size_t)K + scol;
  unsigned short* lA = sA + wave * 8 * 64;
  unsigned short* lB = sB + wave * 8 * 64;

  const int fr = lane & 15;
  const int frs = fr & 7;
  const int kb = lane >> 4;
  const int wm = (wave & 1) * 64, wn = (wave >> 1) * 64;

  for (int kt = 0; kt < K; kt += 64) {
#pragma unroll
    for (int r = 0; r < 4; ++r) {
      gll16(gA + (size_t)r * 32 * K + kt, lA + r * 32 * 64);
      gll16(gB + (size_t)r * 32 * K + kt, lB + r * 32 * 64);
    }
    asm volatile("s_waitcnt vmcnt(0)" ::: "memory");
    __syncthreads();
#pragma unroll
    for (int kk = 0; kk < 64; kk += 32) {
      short8 af[4], bfv[4];
#pragma unroll
      for (int i = 0; i < 4; ++i)
        af[i] = *(const short8*)(sA + (wm + i * 16 + fr) * 64 +
                                 ((((kk >> 3) + kb) ^ frs) * 8));
#pragma unroll
      for (int jj = 0; jj < 4; ++jj)
        bfv[jj] = *(const short8*)(sB + (wn + jj * 16 + fr) * 64 +
                                   ((((kk >> 3) + kb) ^ frs) * 8));
#pragma unroll
      for (int i = 0; i < 4; ++i)
#pragma unroll
        for (int jj = 0; jj < 4; ++jj)
          acc[i][jj] = __builtin_amdgcn_mfma_f32_16x16x32_bf16(
              af[i], bfv[jj], acc[i][jj], 0, 0, 0);
    }
    __syncthreads();
  }

  // C/D mapping: col(n)=lane&15, row(m)=(lane>>4)*4+reg
  const int col = lane & 15;
  const int row4 = (lane >> 4) * 4;

  if (OUT_BF16) {
    unsigned short* sC = smem;  // 128x128 bf16 tile
#pragma unroll
    for (int i = 0; i < 4; ++i)
#pragma unroll
      for (int jj = 0; jj < 4; ++jj)
#pragma unroll
        for (int r = 0; r < 4; ++r)
          sC[(wm + i * 16 + row4 + r) * 128 + wn + jj * 16 + col] =
              f2bf(acc[i][jj][r]);
    __syncthreads();
    unsigned short* C = (unsigned short*)Cp;
#pragma unroll
    for (int s = 0; s < 8; ++s) {
      int row = wave * 32 + s * 4 + (lane >> 4);
      int c8 = (lane & 15) * 8;
      *(ushort8*)(C + (m0 + row) * (size_t)N + n0 + c8) =
          *(const ushort8*)(sC + row * 128 + c8);
    }
  } else {
    float* C = (float*)Cp;
#pragma unroll
    for (int i = 0; i < 4; ++i) {
#pragma unroll
      for (int jj = 0; jj < 4; ++jj) {
#pragma unroll
        for (int r = 0; r < 4; ++r) {
          size_t m = m0 + wm + i * 16 + row4 + r;
          int n = n0 + wn + jj * 16 + col;
          C[m * N + n] = acc[i][jj][r] + bias[n];
        }
      }
    }
  }
}

// ---------- single-pass decoupled-lookback scan, v2 ----------
// u [8][2048][1024] bf16 in-place -> h. 512 blocks = (b, 32-t chunk).
// Thread: 8 ch x 16 t in regs. Lookback: relaxed ballot-spin on up to 63
// flags (one wave-wide load per poll), ONE acquire fence, then all agg
// loads issued with full MLP into a 63-step fmaf chain.

__global__ __launch_bounds__(256, 2) void scan_lb(
    unsigned short* __restrict__ u, const float* __restrict__ Adiag,
    float* __restrict__ aggbuf, unsigned* __restrict__ flags,
    unsigned* __restrict__ ticket) {
  __shared__ float sHalf0[1024];  // half-0 end state per channel
  __shared__ float sCarry[1024];  // chunk carry-in per channel
  __shared__ unsigned svid;

  const int tid = threadIdx.x;
  if (tid == 0) svid = atomicAdd(ticket, 1u);
  __syncthreads();
  const unsigned vid = svid;      // ticket: residency order == chunk order
  const int b = vid & 7;
  const int c = vid >> 3;         // 0..63, ascending in schedule per batch
  const int half = tid >> 7;
  const int ch0 = (tid & 127) * 8;
  const int lane = tid & 63;

  float a[8], a16[8], aL[8];
  *(float4*)&a[0] = *(const float4*)(Adiag + ch0);
  *(float4*)&a[4] = *(const float4*)(Adiag + ch0 + 4);
#pragma unroll
  for (int j = 0; j < 8; ++j) {
    float t = a[j];
    t *= t; t *= t; t *= t; t *= t;  // a^16
    a16[j] = t;
    aL[j] = t * t;                   // a^32
  }

  // local prefix scan over 16 steps, prefixes in regs (bf16-packed)
  const size_t base = ((size_t)(b * SEQ + c * SC_T + half * 16)) * DIM + ch0;
  ushort8 rv[16];
  float s[8];
#pragma unroll
  for (int j = 0; j < 8; ++j) s[j] = 0.f;
#pragma unroll
  for (int t = 0; t < 16; ++t) {
    ushort8 v = *(const ushort8*)(u + base + (size_t)t * DIM);
#pragma unroll
    for (int j = 0; j < 8; ++j) {
      s[j] = fmaf(a[j], s[j], bf2f(v[j]));
      rv[t][j] = f2bf(s[j]);
    }
  }

  if (half == 0) {
    *(float4*)(sHalf0 + ch0) = *(float4*)&s[0];
    *(float4*)(sHalf0 + ch0 + 4) = *(float4*)&s[4];
  }
  __syncthreads();

  // publish chunk aggregate: agg = s1 + a^16 * h0end
  if (half == 1) {
    float* dst = aggbuf + (size_t)(b * SC_CH + c) * 1024 + ch0;
#pragma unroll
    for (int j = 0; j < 8; ++j) dst[j] = fmaf(a16[j], sHalf0[ch0 + j], s[j]);
  }
  __threadfence();  // make agg visible agent-wide (storing threads fence)
  __syncthreads();
  if (tid == 0)
    __hip_atomic_store(&flags[b * SC_CH + c], 1u, __ATOMIC_RELEASE,
                       __HIP_MEMORY_SCOPE_AGENT);

  // lookback (half-0 waves): relaxed ballot-spin, one fence, MLP agg loads
  if (half == 0) {
    const bool need = lane < c;
    const unsigned fi = b * SC_CH + lane;
    while (true) {
      unsigned f = need ? __hip_atomic_load(&flags[fi], __ATOMIC_RELAXED,
                                            __HIP_MEMORY_SCOPE_AGENT)
                        : 1u;
      if (__ballot(f == 0u) == 0ull) break;
      __builtin_amdgcn_s_sleep(1);
    }
    __builtin_amdgcn_fence(__ATOMIC_ACQUIRE, "agent");

    float cb[8];
#pragma unroll
    for (int j = 0; j < 8; ++j) cb[j] = 0.f;
    const float* ab = aggbuf + (size_t)(b * SC_CH) * 1024 + ch0;
    for (int p = 0; p < c; ++p) {
      float4 g0 = *(const float4*)(ab + (size_t)p * 1024);
      float4 g1 = *(const float4*)(ab + (size_t)p * 1024 + 4);
      float g[8] = {g0.x, g0.y, g0.z, g0.w, g1.x, g1.y, g1.z, g1.w};
#pragma unroll
      for (int j = 0; j < 8; ++j) cb[j] = fmaf(aL[j], cb[j], g[j]);
    }
    *(float4*)(sCarry + ch0) = *(float4*)&cb[0];
    *(float4*)(sCarry + ch0 + 4) = *(float4*)&cb[4];
  }
  __syncthreads();

  // apply: h_t = local_t + a^(t+1) * ce;  half0: ce=C, half1: ce=h0end+a^16*C
  float ce[8], apow[8];
#pragma unroll
  for (int j = 0; j < 8; ++j) {
    float C = sCarry[ch0 + j];
    ce[j] = half ? fmaf(a16[j], C, sHalf0[ch0 + j]) : C;
    apow[j] = a[j];
  }
#pragma unroll
  for (int t = 0; t < 16; ++t) {
    ushort8 o;
#pragma unroll
    for (int j = 0; j < 8; ++j) {
      o[j] = f2bf(fmaf(apow[j], ce[j], bf2f(rv[t][j])));
      apow[j] *= a[j];
    }
    *(ushort8*)(u + base + (size_t)t * DIM) = o;
  }
}

// ---------- launcher ----------

extern "C" void kernel_launch(void* const* d_in, const int* in_sizes, int n_in,
                              void* d_out, int out_size, void* d_ws,
                              size_t ws_size, hipStream_t stream) {
  const float* x    = (const float*)d_in[0];
  const float* A    = (const float*)d_in[1];
  const float* B    = (const float*)d_in[2];
  const float* W    = (const float*)d_in[3];
  const float* bias = (const float*)d_in[4];

  char* ws = (char*)d_ws;
  unsigned short* xb = (unsigned short*)ws;               // 32 MB
  unsigned short* ubuf = (unsigned short*)(ws + 33554432);// 32 MB (u -> h)
  unsigned short* Bb = (unsigned short*)(ws + 67108864);  //  2 MB
  unsigned short* Wb = (unsigned short*)(ws + 69206016);  //  2 MB
  float* aggbuf = (float*)(ws + 71303168);                //  2 MB
  unsigned* flags = (unsigned*)(ws + 73400320);           //  512 flags + ticket
  unsigned* ticket = flags + 512;

  cast3_kernel<<<(XN8 + 2 * MN8) / 256, 256, 0, stream>>>(x, B, W, xb, Bb, Wb,
                                                          flags);

  gemm_nt<true><<<(MTOT / 128) * (DIM / 128), 256, 0, stream>>>(
      xb, Bb, (void*)ubuf, nullptr, DIM, DIM);

  scan_lb<<<BATCH * SC_CH, 256, 0, stream>>>(ubuf, A, aggbuf, flags, ticket);

  gemm_nt<false><<<(MTOT / 128) * (DIM / 128), 256, 0, stream>>>(
      ubuf, Wb, d_out, bias, DIM, DIM);
}

// Round 6
// 233.452 us; speedup vs baseline: 1.4095x; 1.4095x over previous
//
#include <hip/hip_runtime.h>
#include <stdint.h>

#define BATCH 8
#define SEQ 2048
#define DIM 1024
#define MTOT (BATCH * SEQ)   // 16384

typedef __attribute__((ext_vector_type(8))) short short8;
typedef __attribute__((ext_vector_type(8))) unsigned short ushort8;
typedef __attribute__((ext_vector_type(4))) float floatx4;

// ---------- helpers ----------

__device__ __forceinline__ unsigned short f2bf(float f) {
  union { float f; unsigned u; } c; c.f = f;
  unsigned u = c.u;
  return (unsigned short)((u + 0x7FFFu + ((u >> 16) & 1u)) >> 16);
}
__device__ __forceinline__ float bf2f(unsigned short h) {
  union { unsigned u; float f; } c; c.u = ((unsigned)h) << 16;
  return c.f;
}

__device__ __forceinline__ void gll16(const void* g, void* l) {
  __builtin_amdgcn_global_load_lds(
      (__attribute__((address_space(1))) void*)(uintptr_t)g,
      (__attribute__((address_space(3))) void*)(uintptr_t)l,
      16, 0, 0);
}

// ---------- cast fp32->bf16 (x, B, W), one float4 -> uint2 per thread ------

#define X4 (MTOT * DIM / 4)   // 4194304
#define M4 (DIM * DIM / 4)    // 262144

__global__ __launch_bounds__(256) void cast3_kernel(
    const float* __restrict__ x, const float* __restrict__ B,
    const float* __restrict__ W, unsigned short* __restrict__ xb,
    unsigned short* __restrict__ Bb, unsigned short* __restrict__ Wb) {
  int i = blockIdx.x * 256 + threadIdx.x;
  const float4* s4;
  uint2* d2;
  int li;
  if (i < X4) {
    s4 = (const float4*)x; d2 = (uint2*)xb; li = i;
  } else if (i < X4 + M4) {
    s4 = (const float4*)B; d2 = (uint2*)Bb; li = i - X4;
  } else {
    s4 = (const float4*)W; d2 = (uint2*)Wb; li = i - X4 - M4;
  }
  float4 v = s4[li];
  uint2 o;
  o.x = (unsigned)f2bf(v.x) | ((unsigned)f2bf(v.y) << 16);
  o.y = (unsigned)f2bf(v.z) | ((unsigned)f2bf(v.w) << 16);
  d2[li] = o;
}

// ---------- GEMM1 fused with chunk-local scan + aggregate publish ----------
// u[m][n] = sum_k x[m][k]*B[n][k]; then per-column prefix scan over the
// 128-row m-tile (one seq chunk), h_local written out bf16, chunk aggregate
// (state at t=127, zero carry-in) published to aggbuf. NO cross-block sync.

__global__ __launch_bounds__(256) void gemm1_fused(
    const unsigned short* __restrict__ A,   // xb bf16 [M x 1024]
    const unsigned short* __restrict__ B,   // Bb bf16 [1024 x 1024]
    unsigned short* __restrict__ u,         // h_local out bf16
    const float* __restrict__ Adiag,
    float* __restrict__ aggbuf) {           // [128][1024] fp32
  __shared__ unsigned short smem[16384];    // sA|sB, reused as sC (32 KB)
  __shared__ float segsum[2][128];
  unsigned short* sA = smem;
  unsigned short* sB = smem + 8192;

  const int tid = threadIdx.x;
  const int wave = tid >> 6, lane = tid & 63;

  // round-2 XCD-aware tile remap (measured FETCH=ideal)
  const int id = blockIdx.x;
  const int xcd = id & 7, j = id >> 3;
  const int mt = xcd * 16 + (j >> 3);
  const int nt = j & 7;
  const size_t m0 = (size_t)mt * 128;
  const int n0 = nt * 128;

  floatx4 acc[4][4] = {};

  const int srow = wave * 8 + (lane >> 3);
  const int scol = (((lane & 7) ^ ((lane >> 3) & 7)) * 8);  // XOR swizzle
  const unsigned short* gA = A + (m0 + srow) * 1024 + scol;
  const unsigned short* gB = B + ((size_t)n0 + srow) * 1024 + scol;
  unsigned short* lA = sA + wave * 8 * 64;
  unsigned short* lB = sB + wave * 8 * 64;

  const int fr = lane & 15;
  const int frs = fr & 7;
  const int kb = lane >> 4;
  const int wm = (wave & 1) * 64, wn = (wave >> 1) * 64;

  for (int kt = 0; kt < 1024; kt += 64) {
#pragma unroll
    for (int r = 0; r < 4; ++r) {
      gll16(gA + (size_t)r * 32 * 1024 + kt, lA + r * 32 * 64);
      gll16(gB + (size_t)r * 32 * 1024 + kt, lB + r * 32 * 64);
    }
    asm volatile("s_waitcnt vmcnt(0)" ::: "memory");
    __syncthreads();
#pragma unroll
    for (int kk = 0; kk < 64; kk += 32) {
      short8 af[4], bfv[4];
#pragma unroll
      for (int i = 0; i < 4; ++i)
        af[i] = *(const short8*)(sA + (wm + i * 16 + fr) * 64 +
                                 ((((kk >> 3) + kb) ^ frs) * 8));
#pragma unroll
      for (int jj = 0; jj < 4; ++jj)
        bfv[jj] = *(const short8*)(sB + (wn + jj * 16 + fr) * 64 +
                                   ((((kk >> 3) + kb) ^ frs) * 8));
#pragma unroll
      for (int i = 0; i < 4; ++i)
#pragma unroll
        for (int jj = 0; jj < 4; ++jj)
          acc[i][jj] = __builtin_amdgcn_mfma_f32_16x16x32_bf16(
              af[i], bfv[jj], acc[i][jj], 0, 0, 0);
    }
    __syncthreads();
  }

  // stage u tile in LDS (C/D map: col=lane&15, row=(lane>>4)*4+reg)
  const int col = lane & 15;
  const int row4 = (lane >> 4) * 4;
  unsigned short* sC = smem;  // 128x128 bf16
#pragma unroll
  for (int i = 0; i < 4; ++i)
#pragma unroll
    for (int jj = 0; jj < 4; ++jj)
#pragma unroll
      for (int r = 0; r < 4; ++r)
        sC[(wm + i * 16 + row4 + r) * 128 + wn + jj * 16 + col] =
            f2bf(acc[i][jj][r]);
  __syncthreads();

  // chunk-local scan: 2 segments x 64 t per column (tid -> col, seg)
  const int colv = tid & 127;
  const int seg = tid >> 7;
  const float a = Adiag[n0 + colv];
  {
    float s = 0.f;
    const int t0 = seg * 64;
#pragma unroll 8
    for (int t = 0; t < 64; ++t) {
      int idx = (t0 + t) * 128 + colv;
      s = fmaf(a, s, bf2f(sC[idx]));
      sC[idx] = f2bf(s);
    }
    segsum[seg][colv] = s;
  }
  __syncthreads();

  // correct rows 64..127 with seg-0 end state; publish aggregate
  {
    float a2 = a * a, a4 = a2 * a2, a8 = a4 * a4, a16 = a8 * a8;
    float a32 = a16 * a16, a64 = a32 * a32;
    const float s0 = segsum[0][colv];
    const int t0 = 64 + seg * 32;
    float apow = seg ? a32 * a : a;  // a^(t0-64+1)
#pragma unroll 8
    for (int t = 0; t < 32; ++t) {
      int idx = (t0 + t) * 128 + colv;
      sC[idx] = f2bf(fmaf(apow, s0, bf2f(sC[idx])));
      apow *= a;
    }
    if (seg)
      aggbuf[(size_t)mt * 1024 + n0 + colv] =
          fmaf(a64, s0, segsum[1][colv]);
  }
  __syncthreads();

  // coalesced 16B h_local stores
#pragma unroll
  for (int s = 0; s < 8; ++s) {
    int row = wave * 32 + s * 4 + (lane >> 4);
    int c8 = (lane & 15) * 8;
    *(ushort8*)(u + (m0 + row) * (size_t)1024 + n0 + c8) =
        *(const ushort8*)(sC + row * 128 + c8);
  }
}

// ---------- combine: exclusive scan of 16 chunk aggregates per (b, n) ------

__global__ __launch_bounds__(256) void combine_kernel(
    const float* __restrict__ agg, float* __restrict__ carry,
    const float* __restrict__ Adiag) {
  const int id = blockIdx.x * 256 + threadIdx.x;  // 0..8191
  const int b = id >> 10, n = id & (DIM - 1);
  float a = Adiag[n];
  float aL = a;
#pragma unroll
  for (int i = 0; i < 7; ++i) aL *= aL;  // a^128
  float s = 0.f;
#pragma unroll
  for (int c = 0; c < 16; ++c) {
    size_t idx = (size_t)(b * 16 + c) * 1024 + n;
    float local = agg[idx];
    carry[idx] = s;           // carry-in for chunk c
    s = fmaf(aL, s, local);
  }
}

// ---------- apply: h = h_local + a^(t_local+1) * carry  (streaming) --------
// XCD-swizzled so each chunk band stays on the XCD that wrote/will read it.

__global__ __launch_bounds__(256) void apply_kernel(
    unsigned short* __restrict__ u, const float* __restrict__ Adiag,
    const float* __restrict__ carry) {
  const int id = blockIdx.x;          // 0..2047
  const int xcd = id & 7, rem = id >> 3;       // rem 0..255
  const int mt = xcd * 16 + (rem >> 4);        // chunk 0..127 (matches gemm map)
  const int sub = rem & 15;                    // 8-row group within chunk
  const int tg = threadIdx.x >> 7;             // 0..1
  const int ch0 = (threadIdx.x & 127) * 8;

  float a[8], cf[8];
  *(float4*)&a[0] = *(const float4*)(Adiag + ch0);
  *(float4*)&a[4] = *(const float4*)(Adiag + ch0 + 4);
  const float* cp = carry + (size_t)mt * 1024 + ch0;
  *(float4*)&cf[0] = *(const float4*)cp;
  *(float4*)&cf[4] = *(const float4*)(cp + 4);

  const int tl = sub * 8 + tg * 4;  // local t of first row (0..124)
  float apow[8];
#pragma unroll
  for (int j = 0; j < 8; ++j)
    apow[j] = __builtin_amdgcn_exp2f(__builtin_amdgcn_logf(a[j]) *
                                     (float)(tl + 1));
  const size_t base = ((size_t)mt * 128 + tl) * DIM + ch0;
#pragma unroll
  for (int s = 0; s < 4; ++s) {
    ushort8 v = *(const ushort8*)(u + base + (size_t)s * DIM);
    ushort8 o;
#pragma unroll
    for (int j = 0; j < 8; ++j) {
      o[j] = f2bf(fmaf(apow[j], cf[j], bf2f(v[j])));
      apow[j] *= a[j];
    }
    *(ushort8*)(u + base + (size_t)s * DIM) = o;
  }
}

// ---------- GEMM2: y = h . W^T + bias (fp32 out) — round-2 verbatim --------

__global__ __launch_bounds__(256) void gemm2(
    const unsigned short* __restrict__ A, const unsigned short* __restrict__ B,
    float* __restrict__ C, const float* __restrict__ bias) {
  __shared__ unsigned short smem[16384];
  unsigned short* sA = smem;
  unsigned short* sB = smem + 8192;

  const int tid = threadIdx.x;
  const int wave = tid >> 6, lane = tid & 63;

  const int id = blockIdx.x;
  const int xcd = id & 7, j = id >> 3;
  const int mt = xcd * 16 + (j >> 3);
  const int nt = j & 7;
  const size_t m0 = (size_t)mt * 128;
  const int n0 = nt * 128;

  floatx4 acc[4][4] = {};

  const int srow = wave * 8 + (lane >> 3);
  const int scol = (((lane & 7) ^ ((lane >> 3) & 7)) * 8);
  const unsigned short* gA = A + (m0 + srow) * 1024 + scol;
  const unsigned short* gB = B + ((size_t)n0 + srow) * 1024 + scol;
  unsigned short* lA = sA + wave * 8 * 64;
  unsigned short* lB = sB + wave * 8 * 64;

  const int fr = lane & 15;
  const int frs = fr & 7;
  const int kb = lane >> 4;
  const int wm = (wave & 1) * 64, wn = (wave >> 1) * 64;

  for (int kt = 0; kt < 1024; kt += 64) {
#pragma unroll
    for (int r = 0; r < 4; ++r) {
      gll16(gA + (size_t)r * 32 * 1024 + kt, lA + r * 32 * 64);
      gll16(gB + (size_t)r * 32 * 1024 + kt, lB + r * 32 * 64);
    }
    asm volatile("s_waitcnt vmcnt(0)" ::: "memory");
    __syncthreads();
#pragma unroll
    for (int kk = 0; kk < 64; kk += 32) {
      short8 af[4], bfv[4];
#pragma unroll
      for (int i = 0; i < 4; ++i)
        af[i] = *(const short8*)(sA + (wm + i * 16 + fr) * 64 +
                                 ((((kk >> 3) + kb) ^ frs) * 8));
#pragma unroll
      for (int jj = 0; jj < 4; ++jj)
        bfv[jj] = *(const short8*)(sB + (wn + jj * 16 + fr) * 64 +
                                   ((((kk >> 3) + kb) ^ frs) * 8));
#pragma unroll
      for (int i = 0; i < 4; ++i)
#pragma unroll
        for (int jj = 0; jj < 4; ++jj)
          acc[i][jj] = __builtin_amdgcn_mfma_f32_16x16x32_bf16(
              af[i], bfv[jj], acc[i][jj], 0, 0, 0);
    }
    __syncthreads();
  }

  const int col = lane & 15;
  const int row4 = (lane >> 4) * 4;
#pragma unroll
  for (int i = 0; i < 4; ++i)
#pragma unroll
    for (int jj = 0; jj < 4; ++jj)
#pragma unroll
      for (int r = 0; r < 4; ++r) {
        size_t m = m0 + wm + i * 16 + row4 + r;
        int n = n0 + wn + jj * 16 + col;
        C[m * 1024 + n] = acc[i][jj][r] + bias[n];
      }
}

// ---------- launcher ----------

extern "C" void kernel_launch(void* const* d_in, const int* in_sizes, int n_in,
                              void* d_out, int out_size, void* d_ws,
                              size_t ws_size, hipStream_t stream) {
  const float* x    = (const float*)d_in[0];
  const float* A    = (const float*)d_in[1];
  const float* B    = (const float*)d_in[2];
  const float* W    = (const float*)d_in[3];
  const float* bias = (const float*)d_in[4];

  char* ws = (char*)d_ws;
  unsigned short* xb   = (unsigned short*)ws;              // 32 MB
  unsigned short* ubuf = (unsigned short*)(ws + 33554432); // 32 MB (h_local->h)
  unsigned short* Bb   = (unsigned short*)(ws + 67108864); //  2 MB
  unsigned short* Wb   = (unsigned short*)(ws + 69206016); //  2 MB
  float* aggbuf        = (float*)(ws + 71303168);          // 512 KB
  float* carry         = (float*)(ws + 71827456);          // 512 KB

  cast3_kernel<<<(X4 + 2 * M4) / 256, 256, 0, stream>>>(x, B, W, xb, Bb, Wb);

  gemm1_fused<<<1024, 256, 0, stream>>>(xb, Bb, ubuf, A, aggbuf);

  combine_kernel<<<32, 256, 0, stream>>>(aggbuf, carry, A);

  apply_kernel<<<2048, 256, 0, stream>>>(ubuf, A, carry);

  gemm2<<<1024, 256, 0, stream>>>(ubuf, Wb, (float*)d_out, bias);
}